// Round 10
// baseline (804.829 us; speedup 1.0000x reference)
//
#include <hip/hip_runtime.h>

typedef _Float16 half8 __attribute__((ext_vector_type(8)));
typedef _Float16 half4 __attribute__((ext_vector_type(4)));
typedef __fp16   pk2   __attribute__((ext_vector_type(2)));
typedef float    f32x4 __attribute__((ext_vector_type(4)));

#define GLOBAL_AS __attribute__((address_space(1)))
#define LDS_AS    __attribute__((address_space(3)))

static constexpr int Bb = 32;
static constexpr int Nn = 2048;
static constexpr int Dd = 1024;
static constexpr int M  = Bb * Nn;   // 65536 rows of the big GEMM

// ---------------------------------------------------------------------------
// B layout (prep0 -> gemm4): chunk = 128 cols x 64 k f16 = 16 KB, staged
// linearly by global_load_lds; unit u = q*128 + s holds col s ^ (2*(q&3)).
// W1TT chunks: [et(4)][t(16)][h(2)].
// A: f32 from `encoded`, reg-staged (dwordx4 -> cvt_pkrtz -> ds_write_b64)
// into a row-major swizzled image: half4 unit (row,kc) at row*16 +
// (kc ^ (2*(row&7))). Write conflict-free (measured 0), read 2-way (free).
// 4 waves / 256 threads, wave owns 128x128 output. acc[8][8] (256 regs) is
// FORCED into AGPRs via inline-asm "+a" MFMA (r9's builtin path kept it in
// VGPRs -> 360 MB scratch spill, 10% MfmaUtil). Arch VGPR demand ~190 < 256;
// total 446 < 512 unified budget at 1 wave/SIMD.
// ---------------------------------------------------------------------------

// Kernel 1: fused prep -- blocks 0-511 pack W1, blocks 512-1023 compute dec.
__global__ void prep0(const float* __restrict__ W1, _Float16* __restrict__ W1TT,
                      const float* __restrict__ ds, const float* __restrict__ W2,
                      float* __restrict__ dec) {
    const int id = blockIdx.x;
    const int tid = threadIdx.x;
    if (id < 512) {
        int g = id * 256 + tid;                   // 131072 half8 units
        int chunk = g >> 10;                      // et*32 + t*2 + h
        int u = g & 1023;
        int q = u >> 7, sc = u & 127;
        int cl = sc ^ (2 * (q & 3));
        int et = chunk >> 5, t = (chunk >> 1) & 15, h = chunk & 1;
        int e  = et * 256 + h * 128 + cl;
        int k0 = t * 64 + q * 8;
        half8 hh;
#pragma unroll
        for (int j = 0; j < 8; ++j)
            hh[j] = (_Float16)W1[(size_t)(k0 + j) * Dd + e];
        *(half8*)(W1TT + (size_t)g * 8) = hh;
    } else {
        __shared__ float part[4][64];
        const int id2 = id - 512;
        const int b = id2 >> 4, ech = id2 & 15;
        int e = ech * 64 + (tid & 63);
        int dc = tid >> 6;
        float acc = 0.f;
#pragma unroll 4
        for (int d = dc * 256; d < dc * 256 + 256; ++d)
            acc += ds[b * Dd + d] * W2[(size_t)d * Dd + e];
        part[dc][tid & 63] = acc;
        __syncthreads();
        if (tid < 64)
            dec[b * Dd + e] = part[0][tid] + part[1][tid]
                            + part[2][tid] + part[3][tid];
    }
}

// ---------------------------------------------------------------------------
// Kernel 2: 256x256 tile, 4 waves (256 thr), wave = 128x128, fused A-staging.
// Per K-tile: issue A-lo (8 dwordx4) + B (8 global_load_lds) for T+1;
// ds_reads: a_ks0(8) b_ks0(8) a_ks1(8) -> LGKM(8) -> issue b_ks1(8) ->
// 64 MFMA (ks0) -> VM(8) write A-lo, issue A-hi (reg reuse, half-tile cover)
// -> LGKM(8) [reads retired in-order; <=8 ds_writes pending] -> 64 MFMA (ks1)
// -> VM(0) write A-hi -> LGKM(0) -> BAR. One barrier per K-tile.
// ---------------------------------------------------------------------------
#define BAR     asm volatile("s_barrier" ::: "memory")
#define LGKM(n) asm volatile("s_waitcnt lgkmcnt(" #n ")" ::: "memory")
#define VM(n)   asm volatile("s_waitcnt vmcnt(" #n ")" ::: "memory")
#define PRIO1   __builtin_amdgcn_s_setprio(1)
#define PRIO0   __builtin_amdgcn_s_setprio(0)

#define RD_A(ks_) do { _Pragma("unroll") \
  for (int m_ = 0; m_ < 8; ++m_) { \
    const int row_ = wrbase + m_ * 16 + l15; \
    a[m_][ks_] = *(const half8*)&lds[As + row_ * 64 \
                    + ((((ks_) * 4 + qq) * 2) ^ rxa) * 4]; \
  } } while (0)

#define RD_B(ks_) do { _Pragma("unroll") \
  for (int n_ = 0; n_ < 8; ++n_) \
    b[n_][ks_] = *(const half8*)&lds[Bs + wcoff \
                    + ((((ks_) * 4 + qq) * 128) + n_ * 16 + l15x) * 8]; \
  } while (0)

// AGPR-accumulator MFMA: "+a" pins acc in the accumulator half of the unified
// register file (the whole point of this round -- r9's builtin kept acc in
// VGPRs and spilled 360 MB).
#define PASS(ks_) do { _Pragma("unroll") \
  for (int m_ = 0; m_ < 8; ++m_) \
  _Pragma("unroll") for (int n_ = 0; n_ < 8; ++n_) \
    asm("v_mfma_f32_16x16x32_f16 %0, %1, %2, %0" \
        : "+a"(acc[m_][n_]) : "v"(a[m_][ks_]), "v"(b[n_][ks_])); \
  } while (0)

__global__ __launch_bounds__(256, 1) void gemm4(
    const float* __restrict__ encA, const _Float16* __restrict__ W1TT,
    const float* __restrict__ dec, const float* __restrict__ vt,
    float* __restrict__ u_part)          // [4][65536]
{
    extern __shared__ _Float16 lds[];    // 65536 halfs = 128 KB

    const int g  = blockIdx.x;                   // 0..1023
    const int wg = (g & 7) * 128 + (g >> 3);     // XCD-chunked swizzle
    const int et    = wg & 3;                    // 4 consecutive wg share mtile
    const int mtile = wg >> 2;                   // 0..255

    const int tid  = threadIdx.x;
    const int lane = tid & 63, wid = tid >> 6;   // 4 waves
    const int wr = wid >> 1, wc = wid & 1;       // wave = 128x128
    const int qq = lane >> 4, l15 = lane & 15;
    const int rxa   = (l15 & 7) * 2;             // A read XOR
    const int l15x  = l15 ^ (2 * qq);            // B read XOR
    const int wrbase = wr * 128;
    const int wcoff  = wc * 8192;                // B chunk select (halfwords)

    f32x4 acc[8][8] = {};                        // 256 AGPRs (via "+a")
    half8 a[8][2], b[8][2];                      // 64 + 64 VGPR
    f32x4 aSt[8];                                // 32, reused lo/hi

    // A staging: thread t covers row p*16 + (t>>4) (per h-half), cols (t&15)*4.
    // Per instr: 16 rows x 256 B contiguous -> ideal coalescing.
    const int arow0 = tid >> 4;                  // 0..15
    const int l16   = tid & 15;
    const float* agp = encA + (((size_t)(mtile * 256 + arow0)) << 10) + l16 * 4;

    const size_t bbase = (size_t)et * 32 * 8192;

    auto issueA = [&](int T, int h) {            // 8 loads: rows h*128 + p*16
        const float* gp = agp + T * 64 + ((size_t)h << 17);
#pragma unroll
        for (int p = 0; p < 8; ++p)
            aSt[p] = *(const f32x4*)(gp + ((size_t)p << 14));   // p*16 rows
    };
    auto writeA = [&](int Tn, int h) {           // 8 conflict-free ds_write_b64
        const int slot = (Tn & 1) << 14;
#pragma unroll
        for (int p = 0; p < 8; ++p) {
            const int row = h * 128 + p * 16 + arow0;   // row&7 == arow0&7
            pk2 c0 = __builtin_amdgcn_cvt_pkrtz(aSt[p][0], aSt[p][1]);
            pk2 c1 = __builtin_amdgcn_cvt_pkrtz(aSt[p][2], aSt[p][3]);
            half4 hh; hh[0] = c0[0]; hh[1] = c0[1]; hh[2] = c1[0]; hh[3] = c1[1];
            *(half4*)&lds[slot + row * 64 + (l16 ^ (2 * (arow0 & 7))) * 4] = hh;
        }
    };
    auto stB = [&](int T) {                      // 8 global_load_lds, 32 KB
        const _Float16* gp0 = W1TT + bbase + (((size_t)T * 2) << 13);
        _Float16* lp0 = lds + 32768 + ((T & 1) << 14);
#pragma unroll
        for (int c = 0; c < 8; ++c)
            __builtin_amdgcn_global_load_lds(
                (const GLOBAL_AS void*)(gp0 + (size_t)(c * 256 + tid) * 8),
                (LDS_AS void*)(lp0 + (c * 256 + wid * 64) * 8), 16, 0, 0);
    };

    // LDS (halfword units): A slot = (T&1)<<14 (32 KB img); B = 32768 + same.

    // prologue: stage tile 0
    issueA(0, 0); stB(0);
    VM(8);  writeA(0, 0);
    issueA(0, 1);
    VM(0);  writeA(0, 1);
    LGKM(0);
    BAR;

#pragma unroll 1
    for (int T = 0; T < 16; ++T) {
        const int As = (T & 1) << 14;
        const int Bs = 32768 + ((T & 1) << 14);
        const bool s = (T < 15);

        if (s) { issueA(T + 1, 0); stB(T + 1); }   // vm in flight: 8 + 8

        RD_A(0);                    // 8 ds_read_b128
        RD_B(0);                    // 8
        RD_A(1);                    // 8   (24 outstanding)
        LGKM(8);                    // ks0 frags resident (a_ks1 may pend)
        RD_B(1);                    // 8
        PRIO1; PASS(0); PRIO0;      // 64 MFMA over ks0
        if (s) {
            VM(8);                  // A-lo regs landed (issued tile start)
            writeA(T + 1, 0);       // 8 ds_write_b64
            issueA(T + 1, 1);       // reuse aSt; half-tile cover
            LGKM(8);                // all 32 reads retired; <=8 writes pend
        } else {
            LGKM(0);
        }
        PRIO1; PASS(1); PRIO0;      // 64 MFMA over ks1
        VM(0);                      // B in LDS; A-hi regs landed
        if (s) writeA(T + 1, 1);
        LGKM(0);                    // writes visible
        BAR;                        // slot flips
    }

    // ---- epilogue: tanh(c + dec) * vt, reduce over this block's 256 cols ----
    const int bidx = mtile >> 3;                 // 8 mtiles per batch row
    float vtv[8], dcv[8];
#pragma unroll
    for (int n = 0; n < 8; ++n) {
        int e = et * 256 + wc * 128 + n * 16 + l15;
        vtv[n] = vt[e];
        dcv[n] = dec[bidx * Dd + e];
    }
    float* usum = (float*)lds;                   // [2 wc][256 rows]
#pragma unroll
    for (int m = 0; m < 8; ++m) {
#pragma unroll
        for (int r = 0; r < 4; ++r) {
            float sv = 0.f;
#pragma unroll
            for (int n = 0; n < 8; ++n) {
                float x  = acc[m][n][r] + dcv[n];
                float ex = __expf(2.f * x);
                sv += (1.f - 2.f * __builtin_amdgcn_rcpf(ex + 1.f)) * vtv[n];
            }
#pragma unroll
            for (int off = 1; off < 16; off <<= 1) sv += __shfl_xor(sv, off, 16);
            if (l15 == 0)
                usum[wc * 256 + wrbase + m * 16 + qq * 4 + r] = sv;
        }
    }
    __syncthreads();
    if (tid < 256)
        u_part[(size_t)et * M + (size_t)mtile * 256 + tid]
            = usum[tid] + usum[256 + tid];
}

// ---------------------------------------------------------------------------
// Kernel 3: masked log-softmax over N=2048 per batch row (4 partial slices).
// ---------------------------------------------------------------------------
__global__ void softmax_k(const float* __restrict__ up, const int* __restrict__ mask,
                          float* __restrict__ out) {
    __shared__ float red[8];
    int b = blockIdx.x, tid = threadIdx.x;
    float l[8];
#pragma unroll
    for (int i = 0; i < 8; ++i) {
        int n = i * 256 + tid;
        float s = up[(size_t)b * Nn + n];
#pragma unroll
        for (int et = 1; et < 4; ++et) s += up[(size_t)et * M + (size_t)b * Nn + n];
        l[i] = s + (mask[b * Nn + n] ? 0.f : -103.278931f);  // ln(2^-149)
    }
    float m = l[0];
#pragma unroll
    for (int i = 1; i < 8; ++i) m = fmaxf(m, l[i]);
#pragma unroll
    for (int o = 32; o >= 1; o >>= 1) m = fmaxf(m, __shfl_xor(m, o, 64));
    if ((tid & 63) == 0) red[tid >> 6] = m;
    __syncthreads();
    m = fmaxf(fmaxf(red[0], red[1]), fmaxf(red[2], red[3]));
    float s = 0.f;
#pragma unroll
    for (int i = 0; i < 8; ++i) s += expf(l[i] - m);
#pragma unroll
    for (int o = 32; o >= 1; o >>= 1) s += __shfl_xor(s, o, 64);
    if ((tid & 63) == 0) red[4 + (tid >> 6)] = s;
    __syncthreads();
    float lse = m + logf(red[4] + red[5] + red[6] + red[7]);
#pragma unroll
    for (int i = 0; i < 8; ++i)
        out[(size_t)b * Nn + i * 256 + tid] = l[i] - lse;
}

// ---------------------------------------------------------------------------
extern "C" void kernel_launch(void* const* d_in, const int* in_sizes, int n_in,
                              void* d_out, int out_size, void* d_ws, size_t ws_size,
                              hipStream_t stream) {
    const float* encoded = (const float*)d_in[0];
    const float* dstate  = (const float*)d_in[1];
    const int*   mask    = (const int*)d_in[2];
    const float* W1      = (const float*)d_in[3];
    const float* W2      = (const float*)d_in[4];
    const float* vt      = (const float*)d_in[5];
    float* out = (float*)d_out;

    // ws layout: u_part (1 MiB) | dec (128 KB) | W1TT (2 MiB)   (~3.2 MB)
    char* ws = (char*)d_ws;
    float*    u_part = (float*)ws;
    float*    dec    = (float*)(ws + (size_t)4 * M * 4);
    _Float16* W1TT   = (_Float16*)(ws + (size_t)4 * M * 4 + (size_t)Bb * Dd * 4);

    static bool attr_done = false;
    if (!attr_done) {
        hipFuncSetAttribute(reinterpret_cast<const void*>(gemm4),
                            hipFuncAttributeMaxDynamicSharedMemorySize, 131072);
        attr_done = true;
    }

    prep0<<<1024, 256, 0, stream>>>(W1, W1TT, dstate, W2, dec);
    gemm4<<<1024, 256, 131072, stream>>>(encoded, W1TT, dec, vt, u_part);
    softmax_k<<<32, 256, 0, stream>>>(u_part, mask, out);
}

// Round 11
// 547.449 us; speedup vs baseline: 1.4701x; 1.4701x over previous
//
#include <hip/hip_runtime.h>

typedef _Float16 half8 __attribute__((ext_vector_type(8)));
typedef _Float16 half4 __attribute__((ext_vector_type(4)));
typedef __fp16   pk2   __attribute__((ext_vector_type(2)));
typedef float    f32x4 __attribute__((ext_vector_type(4)));

#define GLOBAL_AS __attribute__((address_space(1)))
#define LDS_AS    __attribute__((address_space(3)))

static constexpr int Bb = 32;
static constexpr int Nn = 2048;
static constexpr int Dd = 1024;
static constexpr int M  = Bb * Nn;   // 65536 rows of the big GEMM

// ---------------------------------------------------------------------------
// REVERT to the r7 chassis (best measured: gemm 224 us, total 523.7) with ONE
// schedule change: A-image ds_writes moved BEFORE the q3/q4 MFMA block
// (counted LGKM(8) gate) so they drain under MFMA instead of serializing
// before the barrier. 4-wave/"+a" arm abandoned (2x spill failures).
//
// B layout (prep0 -> gemm8): chunk = 128 cols x 64 k f16 = 16 KB, staged
// linearly by global_load_lds; unit u = q*128 + s holds col s ^ (2*(q&3)).
// W1TT chunks: [et(4)][t(16)][h(2)].
// A: f32 from `encoded`, reg-staged (8 dwordx4 -> cvt_pkrtz -> 8 ds_write_b64)
// into a row-major swizzled image: half4 unit (row,kc) at row*16 +
// (kc ^ (2*(row&7))). Write conflict-free (measured 0), read 2-way (free).
// ---------------------------------------------------------------------------

// Kernel 1: fused prep -- blocks 0-511 pack W1, blocks 512-1023 compute dec.
// (verified passing in r9/r10)
__global__ void prep0(const float* __restrict__ W1, _Float16* __restrict__ W1TT,
                      const float* __restrict__ ds, const float* __restrict__ W2,
                      float* __restrict__ dec) {
    const int id = blockIdx.x;
    const int tid = threadIdx.x;
    if (id < 512) {
        int g = id * 256 + tid;                   // 131072 half8 units
        int chunk = g >> 10;                      // et*32 + t*2 + h
        int u = g & 1023;
        int q = u >> 7, sc = u & 127;
        int cl = sc ^ (2 * (q & 3));
        int et = chunk >> 5, t = (chunk >> 1) & 15, h = chunk & 1;
        int e  = et * 256 + h * 128 + cl;
        int k0 = t * 64 + q * 8;
        half8 hh;
#pragma unroll
        for (int j = 0; j < 8; ++j)
            hh[j] = (_Float16)W1[(size_t)(k0 + j) * Dd + e];
        *(half8*)(W1TT + (size_t)g * 8) = hh;
    } else {
        __shared__ float part[4][64];
        const int id2 = id - 512;
        const int b = id2 >> 4, ech = id2 & 15;
        int e = ech * 64 + (tid & 63);
        int dc = tid >> 6;
        float acc = 0.f;
#pragma unroll 4
        for (int d = dc * 256; d < dc * 256 + 256; ++d)
            acc += ds[b * Dd + d] * W2[(size_t)d * Dd + e];
        part[dc][tid & 63] = acc;
        __syncthreads();
        if (tid < 64)
            dec[b * Dd + e] = part[0][tid] + part[1][tid]
                            + part[2][tid] + part[3][tid];
    }
}

// ---------------------------------------------------------------------------
// Kernel 2: 256x256 tile, 8 waves, fused f32->f16 A-staging (r7 chassis).
// Per K-tile: issue 8 A dwordx4 + 4 B global_load_lds for T+1; ds_read +
// counted-lgkm quadrant overlap (q1: LGKM(4), q2: LGKM(0)); RD_A h1;
// VM(4) -> writeA(T+1) EARLY; LGKM(8) [8 h1-reads retired in-order, 8 writes
// drain under q3/q4 MFMA]; q3 q4; VM(0); LGKM(0); BAR. One barrier per tile.
// ---------------------------------------------------------------------------
#define BAR     asm volatile("s_barrier" ::: "memory")
#define LGKM(n) asm volatile("s_waitcnt lgkmcnt(" #n ")" ::: "memory")
#define VM(n)   asm volatile("s_waitcnt vmcnt(" #n ")" ::: "memory")
#define PRIO1   __builtin_amdgcn_s_setprio(1)
#define PRIO0   __builtin_amdgcn_s_setprio(0)

// A image: half4 unit (row,kc) -> halfword addr (row*16 + (kc ^ ((row&7)*2)))*4
#define RD_A(dst, base) do { _Pragma("unroll") \
  for (int ks = 0; ks < 2; ++ks) { \
    _Pragma("unroll") for (int m2 = 0; m2 < 4; ++m2) { \
      const int row_ = m2 * 32 + rA; \
      const int kc0_ = (ks * 4 + qq) * 2; \
      dst[m2][ks] = *(const half8*)&lds[(base) + (row_ * 16 + (kc0_ ^ rxa)) * 4]; \
    } } } while (0)

#define RD_B(dst, base) do { _Pragma("unroll") \
  for (int ks = 0; ks < 2; ++ks) { const int qb = ((ks * 4 + qq) * 128) * 8; \
    _Pragma("unroll") for (int j2 = 0; j2 < 2; ++j2) \
      dst[j2][ks] = *(const half8*)&lds[(base) + qb + (j2 * 64 + rB) * 8]; } } while (0)

#define MFMAQ(A_, B_, ro, co) do { \
  _Pragma("unroll") for (int m2 = 0; m2 < 4; ++m2) \
  _Pragma("unroll") for (int j2 = 0; j2 < 2; ++j2) { \
    acc[(ro) + m2][(co) + j2] = __builtin_amdgcn_mfma_f32_16x16x32_f16( \
        A_[m2][0], B_[j2][0], acc[(ro) + m2][(co) + j2], 0, 0, 0); \
    acc[(ro) + m2][(co) + j2] = __builtin_amdgcn_mfma_f32_16x16x32_f16( \
        A_[m2][1], B_[j2][1], acc[(ro) + m2][(co) + j2], 0, 0, 0); } } while (0)

__global__ __launch_bounds__(512, 2) void gemm8(
    const float* __restrict__ encA, const _Float16* __restrict__ W1TT,
    const float* __restrict__ dec, const float* __restrict__ vt,
    float* __restrict__ u_part)          // [4][65536]
{
    extern __shared__ _Float16 lds[];    // 65536 halfs = 128 KB

    const int g  = blockIdx.x;                   // 0..1023
    const int wg = (g & 7) * 128 + (g >> 3);     // XCD-chunked swizzle (1024%8==0)
    const int et    = wg & 3;                    // 4 consecutive wg share mtile
    const int mtile = wg >> 2;                   //  -> A slab L2-shared per XCD

    const int tid  = threadIdx.x;
    const int lane = tid & 63, wid = tid >> 6;
    const int wr = wid >> 2, wc = wid & 3;
    const int qq = lane >> 4, l15 = lane & 15;
    const int l15s = l15 ^ (2 * qq);             // B read-side bank swizzle
    const int rA = wr * 16 + l15;                // A rows: plain (layout swizzles)
    const int rxa = (l15 & 7) * 2;               // A read XOR (row&7)*2
    const int rB = wc * 16 + l15s;

    f32x4 acc[8][4] = {};
    half8 a[4][2], b0[2][2], b1[2][2];
    f32x4 aSt[8];

    // A staging geometry: instr p covers rows p*32 + (tid>>4); lane covers
    // cols l16*4..+4 of the 64-wide K-slab (4 rows x 256 B contiguous/instr).
    const int arow0 = tid >> 4;                  // 0..31
    const int l16   = tid & 15;
    const float* agp = encA + (((size_t)(mtile * 256 + arow0)) << 10) + l16 * 4;

    const size_t bbase = (size_t)et * 32 * 8192;
    const int uoff = tid * 8;                    // per-thread 16B within chunk

    auto issueA = [&](int T) {
        const float* gp = agp + T * 64;
#pragma unroll
        for (int p = 0; p < 8; ++p)
            aSt[p] = *(const f32x4*)(gp + ((size_t)p << 15));   // p*32 rows
    };
    auto writeA = [&](int Tn) {
        const int base = (Tn & 1) << 14;         // A slot base (halfwords)
#pragma unroll
        for (int p = 0; p < 8; ++p) {
            const int rf = p * 32 + arow0;
            const int h  = rf >> 7, row = rf & 127;
            pk2 c0 = __builtin_amdgcn_cvt_pkrtz(aSt[p][0], aSt[p][1]);
            pk2 c1 = __builtin_amdgcn_cvt_pkrtz(aSt[p][2], aSt[p][3]);
            half4 hh; hh[0] = c0[0]; hh[1] = c0[1]; hh[2] = c1[0]; hh[3] = c1[1];
            *(half4*)&lds[base + h * 8192
                          + (row * 16 + (l16 ^ ((row & 7) * 2))) * 4] = hh;
        }
    };
    auto stB = [&](int T, int h) {
        const _Float16* gp = W1TT + bbase + ((size_t)(T * 2 + h) << 13) + uoff;
        _Float16* lp = lds + (32768 + (((T & 1) * 2 + h) << 13) + (wid << 9));
        __builtin_amdgcn_global_load_lds((const GLOBAL_AS void*)gp,
                                         (LDS_AS void*)lp, 16, 0, 0);
        __builtin_amdgcn_global_load_lds((const GLOBAL_AS void*)(gp + 4096),
                                         (LDS_AS void*)(lp + 4096), 16, 0, 0);
    };

    // LDS bases (halfword units): tile slot = T&1.
    // A: slot0 h0=0, h1=8192 ; slot1 h0=16384, h1=24576.  B: +32768 each.

    // prologue: stage tile 0 (A via reg path, B via global_load_lds)
    issueA(0); stB(0, 0); stB(0, 1);
    VM(4);                                       // A8 landed (B4 outstanding)
    writeA(0);
    VM(0); LGKM(0);
    BAR;

#pragma unroll 2
    for (int T = 0; T < 16; ++T) {
        const int As  = (T & 1) << 14;           // A slot base (halfwords)
        const int Bs2 = 32768 + ((T & 1) << 14); // B slot base
        const bool s = (T < 15);

        // staging for tile T+1 first: maximizes in-flight slack
        if (s) { issueA(T + 1); stB(T + 1, 0); stB(T + 1, 1); }

        // tile T compute with counted-lgkm quadrant overlap
        RD_A(a, As);                 // 8 ds_read_b128 (rows 0..127)
        RD_B(b0, Bs2);               // 4
        RD_B(b1, Bs2 + 8192);        // 4
        LGKM(4);                     // a + b0 resident (b1 draining)
        PRIO1; MFMAQ(a, b0, 0, 0); PRIO0;
        LGKM(0);                     // b1 resident
        PRIO1; MFMAQ(a, b1, 0, 2); PRIO0;
        RD_A(a, As + 8192);          // rows 128..255 (WAR on a: safe, q2 issued)
        if (s) {
            VM(4);                   // 8 A-regs landed (4 B still in flight)
            writeA(T + 1);           // 8 ds_write_b64 -> other slot (EARLY)
            LGKM(8);                 // 8 h1-reads retired (DS in-order);
                                     // the 8 writes drain UNDER q3/q4 MFMA
        } else {
            LGKM(0);
        }
        PRIO1; MFMAQ(a, b0, 4, 0); MFMAQ(a, b1, 4, 2); PRIO0;

        VM(0);                       // B landed (issued ~3000 cyc ago)
        LGKM(0);                     // writes visible (already drained)
        BAR;                         // slot T&1 free; T+1 readable
    }

    // ---- epilogue: tanh(c + dec) * vt, reduce over this block's 256 cols ----
    const int b = mtile >> 3;                    // 8 mtiles per batch row
    float vtv[4], dcv[4];
#pragma unroll
    for (int nf = 0; nf < 4; ++nf) {
        int e = et * 256 + (nf >> 1) * 128 + (nf & 1) * 64 + wc * 16 + l15;
        vtv[nf] = vt[e];
        dcv[nf] = dec[b * Dd + e];
    }
    float* usum = (float*)lds;   // [4 wc][256 rows]; all staging drained
#pragma unroll
    for (int hm = 0; hm < 8; ++hm) {
        const int h = hm >> 2, mq = hm & 3;
#pragma unroll
        for (int r = 0; r < 4; ++r) {
            float sv = 0.f;
#pragma unroll
            for (int nf = 0; nf < 4; ++nf) {
                float x  = acc[hm][nf][r] + dcv[nf];
                float ex = __expf(2.f * x);
                sv += (1.f - 2.f * __builtin_amdgcn_rcpf(ex + 1.f)) * vtv[nf];
            }
#pragma unroll
            for (int off = 1; off < 16; off <<= 1) sv += __shfl_xor(sv, off, 16);
            if (l15 == 0)
                usum[wc * 256 + h * 128 + mq * 32 + wr * 16 + qq * 4 + r] = sv;
        }
    }
    __syncthreads();
    if (tid < 256) {
        float v = usum[tid] + usum[256 + tid] + usum[512 + tid] + usum[768 + tid];
        u_part[(size_t)et * M + (size_t)mtile * 256 + tid] = v;
    }
}

// ---------------------------------------------------------------------------
// Kernel 3: masked log-softmax over N=2048 per batch row (4 partial slices).
// ---------------------------------------------------------------------------
__global__ void softmax_k(const float* __restrict__ up, const int* __restrict__ mask,
                          float* __restrict__ out) {
    __shared__ float red[8];
    int b = blockIdx.x, tid = threadIdx.x;
    float l[8];
#pragma unroll
    for (int i = 0; i < 8; ++i) {
        int n = i * 256 + tid;
        float s = up[(size_t)b * Nn + n];
#pragma unroll
        for (int et = 1; et < 4; ++et) s += up[(size_t)et * M + (size_t)b * Nn + n];
        l[i] = s + (mask[b * Nn + n] ? 0.f : -103.278931f);  // ln(2^-149)
    }
    float m = l[0];
#pragma unroll
    for (int i = 1; i < 8; ++i) m = fmaxf(m, l[i]);
#pragma unroll
    for (int o = 32; o >= 1; o >>= 1) m = fmaxf(m, __shfl_xor(m, o, 64));
    if ((tid & 63) == 0) red[tid >> 6] = m;
    __syncthreads();
    m = fmaxf(fmaxf(red[0], red[1]), fmaxf(red[2], red[3]));
    float s = 0.f;
#pragma unroll
    for (int i = 0; i < 8; ++i) s += expf(l[i] - m);
#pragma unroll
    for (int o = 32; o >= 1; o >>= 1) s += __shfl_xor(s, o, 64);
    if ((tid & 63) == 0) red[4 + (tid >> 6)] = s;
    __syncthreads();
    float lse = m + logf(red[4] + red[5] + red[6] + red[7]);
#pragma unroll
    for (int i = 0; i < 8; ++i)
        out[(size_t)b * Nn + i * 256 + tid] = l[i] - lse;
}

// ---------------------------------------------------------------------------
extern "C" void kernel_launch(void* const* d_in, const int* in_sizes, int n_in,
                              void* d_out, int out_size, void* d_ws, size_t ws_size,
                              hipStream_t stream) {
    const float* encoded = (const float*)d_in[0];
    const float* dstate  = (const float*)d_in[1];
    const int*   mask    = (const int*)d_in[2];
    const float* W1      = (const float*)d_in[3];
    const float* W2      = (const float*)d_in[4];
    const float* vt      = (const float*)d_in[5];
    float* out = (float*)d_out;

    // ws layout: u_part (1 MiB) | dec (128 KB) | W1TT (2 MiB)   (~3.2 MB)
    char* ws = (char*)d_ws;
    float*    u_part = (float*)ws;
    float*    dec    = (float*)(ws + (size_t)4 * M * 4);
    _Float16* W1TT   = (_Float16*)(ws + (size_t)4 * M * 4 + (size_t)Bb * Dd * 4);

    static bool attr_done = false;
    if (!attr_done) {
        hipFuncSetAttribute(reinterpret_cast<const void*>(gemm8),
                            hipFuncAttributeMaxDynamicSharedMemorySize, 131072);
        attr_done = true;
    }

    prep0<<<1024, 256, 0, stream>>>(W1, W1TT, dstate, W2, dec);
    gemm8<<<1024, 512, 131072, stream>>>(encoded, W1TT, dec, vt, u_part);
    softmax_k<<<32, 256, 0, stream>>>(u_part, mask, out);
}

// Round 12
// 525.077 us; speedup vs baseline: 1.5328x; 1.0426x over previous
//
#include <hip/hip_runtime.h>

typedef _Float16 half8 __attribute__((ext_vector_type(8)));
typedef _Float16 half4 __attribute__((ext_vector_type(4)));
typedef __fp16   pk2   __attribute__((ext_vector_type(2)));
typedef float    f32x4 __attribute__((ext_vector_type(4)));

#define GLOBAL_AS __attribute__((address_space(1)))
#define LDS_AS    __attribute__((address_space(3)))

static constexpr int Bb = 32;
static constexpr int Nn = 2048;
static constexpr int Dd = 1024;
static constexpr int M  = Bb * Nn;   // 65536 rows of the big GEMM

// ---------------------------------------------------------------------------
// CONSOLIDATION: exact r7 gemm loop (best measured: 224 us gemm, 523.7 total)
// + fused prep0 (verified r9/r10). r8/r11 write-reorderings and r9/r10
// 4-wave/AGPR arm all regressed; the r7 tail-write placement is the measured
// optimum of this chassis.
//
// B layout (prep0 -> gemm8): chunk = 128 cols x 64 k f16 = 16 KB, staged
// linearly by global_load_lds; unit u = q*128 + s holds col s ^ (2*(q&3)).
// W1TT chunks: [et(4)][t(16)][h(2)].
// A: f32 from `encoded`, reg-staged (8 dwordx4 -> cvt_pkrtz -> 8 ds_write_b64)
// into a row-major swizzled image: half4 unit (row,kc) at row*16 +
// (kc ^ (2*(row&7))). Write conflict-free (measured 0), read 2-way (free).
// ---------------------------------------------------------------------------

// Kernel 1: fused prep -- blocks 0-511 pack W1, blocks 512-1023 compute dec.
__global__ void prep0(const float* __restrict__ W1, _Float16* __restrict__ W1TT,
                      const float* __restrict__ ds, const float* __restrict__ W2,
                      float* __restrict__ dec) {
    const int id = blockIdx.x;
    const int tid = threadIdx.x;
    if (id < 512) {
        int g = id * 256 + tid;                   // 131072 half8 units
        int chunk = g >> 10;                      // et*32 + t*2 + h
        int u = g & 1023;
        int q = u >> 7, sc = u & 127;
        int cl = sc ^ (2 * (q & 3));
        int et = chunk >> 5, t = (chunk >> 1) & 15, h = chunk & 1;
        int e  = et * 256 + h * 128 + cl;
        int k0 = t * 64 + q * 8;
        half8 hh;
#pragma unroll
        for (int j = 0; j < 8; ++j)
            hh[j] = (_Float16)W1[(size_t)(k0 + j) * Dd + e];
        *(half8*)(W1TT + (size_t)g * 8) = hh;
    } else {
        __shared__ float part[4][64];
        const int id2 = id - 512;
        const int b = id2 >> 4, ech = id2 & 15;
        int e = ech * 64 + (tid & 63);
        int dc = tid >> 6;
        float acc = 0.f;
#pragma unroll 4
        for (int d = dc * 256; d < dc * 256 + 256; ++d)
            acc += ds[b * Dd + d] * W2[(size_t)d * Dd + e];
        part[dc][tid & 63] = acc;
        __syncthreads();
        if (tid < 64)
            dec[b * Dd + e] = part[0][tid] + part[1][tid]
                            + part[2][tid] + part[3][tid];
    }
}

// ---------------------------------------------------------------------------
// Kernel 2: 256x256 tile, 8 waves, fused f32->f16 A-staging (EXACT r7 loop).
// Per K-tile: issue 8 A dwordx4 + 4 B global_load_lds for T+1; ds_read +
// counted-lgkm quadrant overlap (q1: LGKM(4), q2: LGKM(0)); RD_A h1; LGKM(0);
// q3 q4; VM(4) -> writeA(T+1); VM(0); LGKM(0); BAR. One barrier per K-tile.
// ---------------------------------------------------------------------------
#define BAR     asm volatile("s_barrier" ::: "memory")
#define LGKM(n) asm volatile("s_waitcnt lgkmcnt(" #n ")" ::: "memory")
#define VM(n)   asm volatile("s_waitcnt vmcnt(" #n ")" ::: "memory")
#define PRIO1   __builtin_amdgcn_s_setprio(1)
#define PRIO0   __builtin_amdgcn_s_setprio(0)

// A image: half4 unit (row,kc) -> halfword addr (row*16 + (kc ^ ((row&7)*2)))*4
#define RD_A(dst, base) do { _Pragma("unroll") \
  for (int ks = 0; ks < 2; ++ks) { \
    _Pragma("unroll") for (int m2 = 0; m2 < 4; ++m2) { \
      const int row_ = m2 * 32 + rA; \
      const int kc0_ = (ks * 4 + qq) * 2; \
      dst[m2][ks] = *(const half8*)&lds[(base) + (row_ * 16 + (kc0_ ^ rxa)) * 4]; \
    } } } while (0)

#define RD_B(dst, base) do { _Pragma("unroll") \
  for (int ks = 0; ks < 2; ++ks) { const int qb = ((ks * 4 + qq) * 128) * 8; \
    _Pragma("unroll") for (int j2 = 0; j2 < 2; ++j2) \
      dst[j2][ks] = *(const half8*)&lds[(base) + qb + (j2 * 64 + rB) * 8]; } } while (0)

#define MFMAQ(A_, B_, ro, co) do { \
  _Pragma("unroll") for (int m2 = 0; m2 < 4; ++m2) \
  _Pragma("unroll") for (int j2 = 0; j2 < 2; ++j2) { \
    acc[(ro) + m2][(co) + j2] = __builtin_amdgcn_mfma_f32_16x16x32_f16( \
        A_[m2][0], B_[j2][0], acc[(ro) + m2][(co) + j2], 0, 0, 0); \
    acc[(ro) + m2][(co) + j2] = __builtin_amdgcn_mfma_f32_16x16x32_f16( \
        A_[m2][1], B_[j2][1], acc[(ro) + m2][(co) + j2], 0, 0, 0); } } while (0)

__global__ __launch_bounds__(512, 2) void gemm8(
    const float* __restrict__ encA, const _Float16* __restrict__ W1TT,
    const float* __restrict__ dec, const float* __restrict__ vt,
    float* __restrict__ u_part)          // [4][65536]
{
    extern __shared__ _Float16 lds[];    // 65536 halfs = 128 KB

    const int g  = blockIdx.x;                   // 0..1023
    const int wg = (g & 7) * 128 + (g >> 3);     // XCD-chunked swizzle (1024%8==0)
    const int et    = wg & 3;                    // 4 consecutive wg share mtile
    const int mtile = wg >> 2;                   //  -> A slab L2-shared per XCD

    const int tid  = threadIdx.x;
    const int lane = tid & 63, wid = tid >> 6;
    const int wr = wid >> 2, wc = wid & 3;
    const int qq = lane >> 4, l15 = lane & 15;
    const int l15s = l15 ^ (2 * qq);             // B read-side bank swizzle
    const int rA = wr * 16 + l15;                // A rows: plain (layout swizzles)
    const int rxa = (l15 & 7) * 2;               // A read XOR (row&7)*2
    const int rB = wc * 16 + l15s;

    f32x4 acc[8][4] = {};
    half8 a[4][2], b0[2][2], b1[2][2];
    f32x4 aSt[8];

    // A staging geometry: instr p covers rows p*32 + (tid>>4); lane covers
    // cols l16*4..+4 of the 64-wide K-slab (4 rows x 256 B contiguous/instr).
    const int arow0 = tid >> 4;                  // 0..31
    const int l16   = tid & 15;
    const float* agp = encA + (((size_t)(mtile * 256 + arow0)) << 10) + l16 * 4;

    const size_t bbase = (size_t)et * 32 * 8192;
    const int uoff = tid * 8;                    // per-thread 16B within chunk

    auto issueA = [&](int T) {
        const float* gp = agp + T * 64;
#pragma unroll
        for (int p = 0; p < 8; ++p)
            aSt[p] = *(const f32x4*)(gp + ((size_t)p << 15));   // p*32 rows
    };
    auto writeA = [&](int Tn) {
        const int base = (Tn & 1) << 14;         // A slot base (halfwords)
#pragma unroll
        for (int p = 0; p < 8; ++p) {
            const int rf = p * 32 + arow0;
            const int h  = rf >> 7, row = rf & 127;
            pk2 c0 = __builtin_amdgcn_cvt_pkrtz(aSt[p][0], aSt[p][1]);
            pk2 c1 = __builtin_amdgcn_cvt_pkrtz(aSt[p][2], aSt[p][3]);
            half4 hh; hh[0] = c0[0]; hh[1] = c0[1]; hh[2] = c1[0]; hh[3] = c1[1];
            *(half4*)&lds[base + h * 8192
                          + (row * 16 + (l16 ^ ((row & 7) * 2))) * 4] = hh;
        }
    };
    auto stB = [&](int T, int h) {
        const _Float16* gp = W1TT + bbase + ((size_t)(T * 2 + h) << 13) + uoff;
        _Float16* lp = lds + (32768 + (((T & 1) * 2 + h) << 13) + (wid << 9));
        __builtin_amdgcn_global_load_lds((const GLOBAL_AS void*)gp,
                                         (LDS_AS void*)lp, 16, 0, 0);
        __builtin_amdgcn_global_load_lds((const GLOBAL_AS void*)(gp + 4096),
                                         (LDS_AS void*)(lp + 4096), 16, 0, 0);
    };

    // LDS bases (halfword units): tile slot = T&1.
    // A: slot0 h0=0, h1=8192 ; slot1 h0=16384, h1=24576.  B: +32768 each.

    // prologue: stage tile 0 (A via reg path, B via global_load_lds)
    issueA(0); stB(0, 0); stB(0, 1);
    VM(4);                                       // A8 landed (B4 outstanding)
    writeA(0);
    VM(0); LGKM(0);
    BAR;

#pragma unroll 2
    for (int T = 0; T < 16; ++T) {
        const int As  = (T & 1) << 14;           // A slot base (halfwords)
        const int Bs2 = 32768 + ((T & 1) << 14); // B slot base
        const bool s = (T < 15);

        // staging for tile T+1 first: maximizes in-flight slack
        if (s) { issueA(T + 1); stB(T + 1, 0); stB(T + 1, 1); }

        // tile T compute with counted-lgkm quadrant overlap
        RD_A(a, As);                 // 8 ds_read_b128 (rows 0..127)
        RD_B(b0, Bs2);               // 4
        RD_B(b1, Bs2 + 8192);        // 4
        LGKM(4);                     // a + b0 resident (b1 draining)
        PRIO1; MFMAQ(a, b0, 0, 0); PRIO0;
        LGKM(0);                     // b1 resident
        PRIO1; MFMAQ(a, b1, 0, 2); PRIO0;
        RD_A(a, As + 8192);          // rows 128..255 (WAR on a: safe, q2 issued)
        LGKM(0);
        PRIO1; MFMAQ(a, b0, 4, 0); MFMAQ(a, b1, 4, 2); PRIO0;

        if (s) { VM(4); writeA(T + 1); }         // A regs landed ~2000 cyc ago
        VM(0); LGKM(0);                          // B landed; ds_writes retired
        BAR;                                     // slot T&1 free; T+1 readable
    }

    // ---- epilogue: tanh(c + dec) * vt, reduce over this block's 256 cols ----
    const int b = mtile >> 3;                    // 8 mtiles per batch row
    float vtv[4], dcv[4];
#pragma unroll
    for (int nf = 0; nf < 4; ++nf) {
        int e = et * 256 + (nf >> 1) * 128 + (nf & 1) * 64 + wc * 16 + l15;
        vtv[nf] = vt[e];
        dcv[nf] = dec[b * Dd + e];
    }
    float* usum = (float*)lds;   // [4 wc][256 rows]; all staging drained
#pragma unroll
    for (int hm = 0; hm < 8; ++hm) {
        const int h = hm >> 2, mq = hm & 3;
#pragma unroll
        for (int r = 0; r < 4; ++r) {
            float sv = 0.f;
#pragma unroll
            for (int nf = 0; nf < 4; ++nf) {
                float x  = acc[hm][nf][r] + dcv[nf];
                float ex = __expf(2.f * x);
                sv += (1.f - 2.f * __builtin_amdgcn_rcpf(ex + 1.f)) * vtv[nf];
            }
#pragma unroll
            for (int off = 1; off < 16; off <<= 1) sv += __shfl_xor(sv, off, 16);
            if (l15 == 0)
                usum[wc * 256 + h * 128 + mq * 32 + wr * 16 + qq * 4 + r] = sv;
        }
    }
    __syncthreads();
    if (tid < 256) {
        float v = usum[tid] + usum[256 + tid] + usum[512 + tid] + usum[768 + tid];
        u_part[(size_t)et * M + (size_t)mtile * 256 + tid] = v;
    }
}

// ---------------------------------------------------------------------------
// Kernel 3: masked log-softmax over N=2048 per batch row (4 partial slices).
// ---------------------------------------------------------------------------
__global__ void softmax_k(const float* __restrict__ up, const int* __restrict__ mask,
                          float* __restrict__ out) {
    __shared__ float red[8];
    int b = blockIdx.x, tid = threadIdx.x;
    float l[8];
#pragma unroll
    for (int i = 0; i < 8; ++i) {
        int n = i * 256 + tid;
        float s = up[(size_t)b * Nn + n];
#pragma unroll
        for (int et = 1; et < 4; ++et) s += up[(size_t)et * M + (size_t)b * Nn + n];
        l[i] = s + (mask[b * Nn + n] ? 0.f : -103.278931f);  // ln(2^-149)
    }
    float m = l[0];
#pragma unroll
    for (int i = 1; i < 8; ++i) m = fmaxf(m, l[i]);
#pragma unroll
    for (int o = 32; o >= 1; o >>= 1) m = fmaxf(m, __shfl_xor(m, o, 64));
    if ((tid & 63) == 0) red[tid >> 6] = m;
    __syncthreads();
    m = fmaxf(fmaxf(red[0], red[1]), fmaxf(red[2], red[3]));
    float s = 0.f;
#pragma unroll
    for (int i = 0; i < 8; ++i) s += expf(l[i] - m);
#pragma unroll
    for (int o = 32; o >= 1; o >>= 1) s += __shfl_xor(s, o, 64);
    if ((tid & 63) == 0) red[4 + (tid >> 6)] = s;
    __syncthreads();
    float lse = m + logf(red[4] + red[5] + red[6] + red[7]);
#pragma unroll
    for (int i = 0; i < 8; ++i)
        out[(size_t)b * Nn + i * 256 + tid] = l[i] - lse;
}

// ---------------------------------------------------------------------------
extern "C" void kernel_launch(void* const* d_in, const int* in_sizes, int n_in,
                              void* d_out, int out_size, void* d_ws, size_t ws_size,
                              hipStream_t stream) {
    const float* encoded = (const float*)d_in[0];
    const float* dstate  = (const float*)d_in[1];
    const int*   mask    = (const int*)d_in[2];
    const float* W1      = (const float*)d_in[3];
    const float* W2      = (const float*)d_in[4];
    const float* vt      = (const float*)d_in[5];
    float* out = (float*)d_out;

    // ws layout: u_part (1 MiB) | dec (128 KB) | W1TT (2 MiB)   (~3.2 MB)
    char* ws = (char*)d_ws;
    float*    u_part = (float*)ws;
    float*    dec    = (float*)(ws + (size_t)4 * M * 4);
    _Float16* W1TT   = (_Float16*)(ws + (size_t)4 * M * 4 + (size_t)Bb * Dd * 4);

    static bool attr_done = false;
    if (!attr_done) {
        hipFuncSetAttribute(reinterpret_cast<const void*>(gemm8),
                            hipFuncAttributeMaxDynamicSharedMemorySize, 131072);
        attr_done = true;
    }

    prep0<<<1024, 256, 0, stream>>>(W1, W1TT, dstate, W2, dec);
    gemm8<<<1024, 512, 131072, stream>>>(encoded, W1TT, dec, vt, u_part);
    softmax_k<<<32, 256, 0, stream>>>(u_part, mask, out);
}